// Round 1
// baseline (177.125 us; speedup 1.0000x reference)
//
#include <hip/hip_runtime.h>
#include <math.h>

#define NUM_EMB 512
#define DIMV 65          // 65
#define DD   64          // DIM-1
#define BB   2048
#define NN   256

__device__ __forceinline__ float gelu_exact(float x) {
    return 0.5f * x * (1.0f + erff(x * 0.7071067811865475f));
}

// ---------------------------------------------------------------------------
// Kernel 1: build W[e] = H[e,0] @ H[e,1] @ ... @ H[e,63], scaled last column.
// One 256-thread block per embedding. Thread (r,q): r = t>>2 owns row r of W,
// q = t&3 owns 16 columns [16q, 16q+16). Householder right-multiply is a
// matvec + rank-1 update: W <- W - (2/||v||^2) (W v) v^T.
// Also echoes r_idx (as float) into the tail of d_out (4 entries per block).
// ---------------------------------------------------------------------------
__global__ __launch_bounds__(256) void build_W(const float* __restrict__ emb,
                                               const float* __restrict__ flip_sign,
                                               const int*   __restrict__ r_idx,
                                               float* __restrict__ Wg,
                                               float* __restrict__ out) {
    __shared__ float v_lds[DD * DD];
    __shared__ float s_lds[DD];
    const int e = blockIdx.x;
    const int t = threadIdx.x;
    const int r = t >> 2;
    const int q = t & 3;

    // stage gelu(emb row) -> v_lds (64 Householder vectors of dim 64)
    const float* erow = emb + (size_t)e * (DD * DD);
    #pragma unroll
    for (int p = 0; p < 16; ++p) {
        int idx = p * 256 + t;
        v_lds[idx] = gelu_exact(erow[idx]);
    }

    // r_idx passthrough: output 1 lives at out[BB*NN*DIMV + b]
    if (t < 4) {
        int bi = e * 4 + t;
        out[(size_t)BB * NN * DIMV + bi] = (float)r_idx[bi];
    }
    __syncthreads();

    // s[w] = 2 / ||v_w||^2
    {
        const float* vr = &v_lds[r * DD + q * 16];
        float ss = 0.f;
        #pragma unroll
        for (int k = 0; k < 16; ++k) ss += vr[k] * vr[k];
        ss += __shfl_xor(ss, 1);
        ss += __shfl_xor(ss, 2);
        if (q == 0) s_lds[r] = 2.0f / ss;
    }
    __syncthreads();

    // W = I, distributed: thread holds W[r][16q .. 16q+15]
    float Wq[16];
    #pragma unroll
    for (int k = 0; k < 16; ++k) Wq[k] = ((q * 16 + k) == r) ? 1.0f : 0.0f;

    // 64 sequential Householder right-multiplies
    for (int w = 0; w < DD; ++w) {
        const float* vr = &v_lds[w * DD + q * 16];
        float vv[16];
        *(float4*)&vv[0]  = *(const float4*)&vr[0];
        *(float4*)&vv[4]  = *(const float4*)&vr[4];
        *(float4*)&vv[8]  = *(const float4*)&vr[8];
        *(float4*)&vv[12] = *(const float4*)&vr[12];
        float p = 0.f;
        #pragma unroll
        for (int k = 0; k < 16; ++k) p += Wq[k] * vv[k];
        // reduce partial dot across the 4 threads of this row (lanes t^1, t^2)
        p += __shfl_xor(p, 1);
        p += __shfl_xor(p, 2);
        const float sc = s_lds[w] * p;
        #pragma unroll
        for (int k = 0; k < 16; ++k) Wq[k] -= sc * vv[k];
    }

    // W[:, :, -1] *= flip_sign  (column 63 = q==3, k==15)
    if (q == 3) Wq[15] *= flip_sign[0];

    // store row-major W[e][r][c]
    float* wd = Wg + (((size_t)e * DD + r) * DD) + q * 16;
    *(float4*)&wd[0]  = *(float4*)&Wq[0];
    *(float4*)&wd[4]  = *(float4*)&Wq[4];
    *(float4*)&wd[8]  = *(float4*)&Wq[8];
    *(float4*)&wd[12] = *(float4*)&Wq[12];
}

// ---------------------------------------------------------------------------
// Kernel 2: out[b,n,0] = x[b,n,0];  out[b,n,1+c] = sum_d x[b,n,1+d] * W[rb][d][c]
// Block = 256 threads, handles one b and a 64-row n-tile. W staged in LDS
// (pad 68 for 16B-aligned rows), x tile transposed into LDS (pad 66, 8B rows).
// Thread (i,j) = (t>>4, t&15) computes a 4x4 microtile: rows 4i.., cols 4j..
// ---------------------------------------------------------------------------
#define WPAD 68
#define XPAD 66

__global__ __launch_bounds__(256) void apply_W(const float* __restrict__ x,
                                               const int*   __restrict__ r_idx,
                                               const float* __restrict__ Wg,
                                               float* __restrict__ out) {
    __shared__ float Wl[DD * WPAD];
    __shared__ float xT[DD * XPAD];
    const int blk  = blockIdx.x;
    const int b    = blk >> 2;
    const int tile = blk & 3;
    const int n0   = tile * 64;
    const int t    = threadIdx.x;

    const int e = r_idx[b];

    // stage W[e] -> Wl (row d at offset d*WPAD, 16B aligned since WPAD%4==0)
    const float* wsrc = Wg + (size_t)e * (DD * DD);
    #pragma unroll
    for (int p = 0; p < 4; ++p) {
        int idx = (p * 256 + t) * 4;
        int d = idx >> 6, c = idx & 63;
        *(float4*)&Wl[d * WPAD + c] = *(const float4*)&wsrc[idx];
    }

    // stage x tile transposed: xT[d][lr] = x[b, n0+lr, 1+d]; also copy col 0
    {
        const int c  = t & 63;
        const int rr = t >> 6;
        #pragma unroll
        for (int p = 0; p < 16; ++p) {
            int lr = rr + p * 4;
            size_t row = (size_t)b * NN + n0 + lr;
            xT[c * XPAD + lr] = x[row * DIMV + 1 + c];
            if (c == 0) out[row * DIMV] = x[row * DIMV];
        }
    }
    __syncthreads();

    const int i = t >> 4;   // row group: rows 4i..4i+3
    const int j = t & 15;   // col group: cols 4j..4j+3
    float acc[4][4];
    #pragma unroll
    for (int k = 0; k < 4; ++k)
        #pragma unroll
        for (int l = 0; l < 4; ++l) acc[k][l] = 0.f;

    #pragma unroll 8
    for (int d = 0; d < DD; ++d) {
        float4 w4 = *(const float4*)&Wl[d * WPAD + 4 * j];
        float2 xa = *(const float2*)&xT[d * XPAD + 4 * i];
        float2 xb = *(const float2*)&xT[d * XPAD + 4 * i + 2];
        float xs[4] = {xa.x, xa.y, xb.x, xb.y};
        #pragma unroll
        for (int k = 0; k < 4; ++k) {
            acc[k][0] += xs[k] * w4.x;
            acc[k][1] += xs[k] * w4.y;
            acc[k][2] += xs[k] * w4.z;
            acc[k][3] += xs[k] * w4.w;
        }
    }

    #pragma unroll
    for (int k = 0; k < 4; ++k) {
        size_t row = (size_t)b * NN + n0 + 4 * i + k;
        float* op = &out[row * DIMV + 1 + 4 * j];
        op[0] = acc[k][0];
        op[1] = acc[k][1];
        op[2] = acc[k][2];
        op[3] = acc[k][3];
    }
}

extern "C" void kernel_launch(void* const* d_in, const int* in_sizes, int n_in,
                              void* d_out, int out_size, void* d_ws, size_t ws_size,
                              hipStream_t stream) {
    const float* x         = (const float*)d_in[0];
    const int*   r_idx     = (const int*)d_in[1];
    const float* emb       = (const float*)d_in[2];
    const float* flip_sign = (const float*)d_in[3];
    float* out = (float*)d_out;
    float* Wg  = (float*)d_ws;   // 512 * 64 * 64 * 4 = 8 MB scratch

    build_W<<<NUM_EMB, 256, 0, stream>>>(emb, flip_sign, r_idx, Wg, out);
    apply_W<<<BB * 4, 256, 0, stream>>>(x, r_idx, Wg, out);
}

// Round 2
// 115.783 us; speedup vs baseline: 1.5298x; 1.5298x over previous
//
#include <hip/hip_runtime.h>
#include <math.h>

#define NUM_EMB 512
#define DIMV 65          // 65
#define DD   64          // DIM-1
#define BB   2048
#define NN   256

__device__ __forceinline__ float gelu_exact(float x) {
    return 0.5f * x * (1.0f + erff(x * 0.7071067811865475f));
}

// ---------------------------------------------------------------------------
// Kernel 1: build W[e] = H[e,0] @ H[e,1] @ ... @ H[e,63], scaled last column.
// One 256-thread block per embedding. Householder right-multiply as
// matvec + rank-1 update: W <- W - (2/||v||^2) (W v) v^T.
// Also echoes r_idx (as float) into the tail of d_out.
// ---------------------------------------------------------------------------
__global__ __launch_bounds__(256) void build_W(const float* __restrict__ emb,
                                               const float* __restrict__ flip_sign,
                                               const int*   __restrict__ r_idx,
                                               float* __restrict__ Wg,
                                               float* __restrict__ out) {
    __shared__ float v_lds[DD * DD];
    __shared__ float s_lds[DD];
    const int e = blockIdx.x;
    const int t = threadIdx.x;
    const int r = t >> 2;
    const int q = t & 3;

    const float* erow = emb + (size_t)e * (DD * DD);
    #pragma unroll
    for (int p = 0; p < 16; ++p) {
        int idx = p * 256 + t;
        v_lds[idx] = gelu_exact(erow[idx]);
    }

    // r_idx passthrough: output 1 lives at out[BB*NN*DIMV + b]
    if (t < 4) {
        int bi = e * 4 + t;
        out[(size_t)BB * NN * DIMV + bi] = (float)r_idx[bi];
    }
    __syncthreads();

    {
        const float* vr = &v_lds[r * DD + q * 16];
        float ss = 0.f;
        #pragma unroll
        for (int k = 0; k < 16; ++k) ss += vr[k] * vr[k];
        ss += __shfl_xor(ss, 1);
        ss += __shfl_xor(ss, 2);
        if (q == 0) s_lds[r] = 2.0f / ss;
    }
    __syncthreads();

    float Wq[16];
    #pragma unroll
    for (int k = 0; k < 16; ++k) Wq[k] = ((q * 16 + k) == r) ? 1.0f : 0.0f;

    for (int w = 0; w < DD; ++w) {
        const float* vr = &v_lds[w * DD + q * 16];
        float vv[16];
        *(float4*)&vv[0]  = *(const float4*)&vr[0];
        *(float4*)&vv[4]  = *(const float4*)&vr[4];
        *(float4*)&vv[8]  = *(const float4*)&vr[8];
        *(float4*)&vv[12] = *(const float4*)&vr[12];
        float p = 0.f;
        #pragma unroll
        for (int k = 0; k < 16; ++k) p += Wq[k] * vv[k];
        p += __shfl_xor(p, 1);
        p += __shfl_xor(p, 2);
        const float sc = s_lds[w] * p;
        #pragma unroll
        for (int k = 0; k < 16; ++k) Wq[k] -= sc * vv[k];
    }

    if (q == 3) Wq[15] *= flip_sign[0];

    float* wd = Wg + (((size_t)e * DD + r) * DD) + q * 16;
    *(float4*)&wd[0]  = *(float4*)&Wq[0];
    *(float4*)&wd[4]  = *(float4*)&Wq[4];
    *(float4*)&wd[8]  = *(float4*)&Wq[8];
    *(float4*)&wd[12] = *(float4*)&Wq[12];
}

// ---------------------------------------------------------------------------
// Kernel 2: out[b,n,0] = x[b,n,0];  out[b,n,1+c] = sum_d x[b,n,1+d] * W[rb][d][c]
// 512-thread block handles one b and a 128-row n-tile.
//  - x staged NATURALLY: x_lds[128][65] (flat contiguous float4 copy; rows at
//    stride 65 are bank-conflict-free since 65 % 32 == 1).
//  - W staged unpadded: w_lds[64][64].
//  - Thread (r,q) = (t>>2, t&3) owns row r, cols [16q,16q+16): acc[16].
//    Per d: x_d via 4-lane-broadcast ds_read_b32; W row segment via 4
//    near-broadcast ds_read_b128 -> 16 FMAs. LDS 49.7KB -> 3 blocks/CU,
//    24 waves/CU (75% occupancy).
// ---------------------------------------------------------------------------
__global__ __launch_bounds__(512) void apply_W(const float* __restrict__ x,
                                               const int*   __restrict__ r_idx,
                                               const float* __restrict__ Wg,
                                               float* __restrict__ out) {
    __shared__ float x_lds[128 * DIMV];   // 33280 B
    __shared__ float w_lds[DD * DD];      // 16384 B
    const int blk  = blockIdx.x;
    const int b    = blk >> 1;
    const int row0 = (blk & 1) * 128;     // n-offset within b
    const int t    = threadIdx.x;

    const int e = r_idx[b];

    // stage x tile: flat contiguous copy of 128*65 = 8320 floats = 2080 float4
    // base element index (b*256+row0)*65 is divisible by 4 -> 16B aligned
    {
        const float4* xsrc = (const float4*)(x + ((size_t)b * NN + row0) * DIMV);
        float4* xdst = (float4*)x_lds;
        #pragma unroll
        for (int idx = t; idx < 2080; idx += 512) xdst[idx] = xsrc[idx];
    }
    // stage W: 4096 floats = 1024 float4
    {
        const float4* wsrc = (const float4*)(Wg + (size_t)e * (DD * DD));
        float4* wdst = (float4*)w_lds;
        #pragma unroll
        for (int idx = t; idx < 1024; idx += 512) wdst[idx] = wsrc[idx];
    }
    __syncthreads();

    const int r = t >> 2;     // 0..127 row within tile
    const int q = t & 3;      // col quarter

    float acc[16];
    #pragma unroll
    for (int k = 0; k < 16; ++k) acc[k] = 0.f;

    const float* xrow = &x_lds[r * DIMV + 1];
    const float* wq   = &w_lds[16 * q];

    #pragma unroll 8
    for (int d = 0; d < DD; ++d) {
        const float xd = xrow[d];
        const float4 w0 = *(const float4*)&wq[d * DD + 0];
        const float4 w1 = *(const float4*)&wq[d * DD + 4];
        const float4 w2 = *(const float4*)&wq[d * DD + 8];
        const float4 w3 = *(const float4*)&wq[d * DD + 12];
        acc[0]  += xd * w0.x;  acc[1]  += xd * w0.y;
        acc[2]  += xd * w0.z;  acc[3]  += xd * w0.w;
        acc[4]  += xd * w1.x;  acc[5]  += xd * w1.y;
        acc[6]  += xd * w1.z;  acc[7]  += xd * w1.w;
        acc[8]  += xd * w2.x;  acc[9]  += xd * w2.y;
        acc[10] += xd * w2.z;  acc[11] += xd * w2.w;
        acc[12] += xd * w3.x;  acc[13] += xd * w3.y;
        acc[14] += xd * w3.z;  acc[15] += xd * w3.w;
    }

    // store: 16 consecutive floats per thread (quad covers the 64-col row)
    {
        float* op = out + ((size_t)b * NN + row0 + r) * DIMV + 1 + 16 * q;
        #pragma unroll
        for (int k = 0; k < 16; ++k) op[k] = acc[k];
    }
    // col-0 passthrough
    if (t < 128) out[((size_t)b * NN + row0 + t) * DIMV] = x_lds[t * DIMV];
}

extern "C" void kernel_launch(void* const* d_in, const int* in_sizes, int n_in,
                              void* d_out, int out_size, void* d_ws, size_t ws_size,
                              hipStream_t stream) {
    const float* x         = (const float*)d_in[0];
    const int*   r_idx     = (const int*)d_in[1];
    const float* emb       = (const float*)d_in[2];
    const float* flip_sign = (const float*)d_in[3];
    float* out = (float*)d_out;
    float* Wg  = (float*)d_ws;   // 512 * 64 * 64 * 4 = 8 MB scratch

    build_W<<<NUM_EMB, 256, 0, stream>>>(emb, flip_sign, r_idx, Wg, out);
    apply_W<<<BB * 2, 512, 0, stream>>>(x, r_idx, Wg, out);
}